// Round 16
// baseline (58.250 us; speedup 1.0000x reference)
//
#include <hip/hip_runtime.h>
#include <hip/hip_bf16.h>
#include <stdint.h>

#define BATCH 8192
#define DIM   1024
#define BM 128
#define BN 64
#define BK 64
#define STEPS 16                 // DIM / BK
#define BUF 24576                // A 16K + B 8K per stage buffer

typedef __attribute__((ext_vector_type(4))) float f32x4;
typedef __attribute__((ext_vector_type(8))) short bf16x8;
typedef __attribute__((ext_vector_type(8))) unsigned short u16x8;

#define AS1(p) ((const __attribute__((address_space(1))) void*)(p))
#define AS3(p) ((__attribute__((address_space(3))) void*)(p))

__device__ __forceinline__ unsigned short f2bf(float f) {
    union { __hip_bfloat16 h; unsigned short u; } v;
    v.h = __hip_bfloat16(f);
    return v.u;
}
__device__ __forceinline__ float sigma_f(float x) {
    float x2 = x * x;
    return x2 * __builtin_amdgcn_rcpf(1.0f + x2);
}

// ---------------------------------------------------------------------------
// K1: sigma(x) -> bf16 ws + out2 zeros (4096 blocks) | A -> bf16 (512 blocks)
// ---------------------------------------------------------------------------
__global__ __launch_bounds__(256) void prep_kernel(
    const float* __restrict__ x, const float* __restrict__ A,
    unsigned short* __restrict__ sigb, unsigned short* __restrict__ Abf,
    float* __restrict__ out2)
{
    const int i = blockIdx.x * 256 + threadIdx.x;
    if (i < BATCH * DIM / 8) {
        f32x4 v0 = ((const f32x4*)x)[i * 2];
        f32x4 v1 = ((const f32x4*)x)[i * 2 + 1];
        u16x8 sb;
#pragma unroll
        for (int e = 0; e < 4; ++e) {
            sb[e]     = f2bf(sigma_f(v0[e]));
            sb[e + 4] = f2bf(sigma_f(v1[e]));
        }
        ((u16x8*)sigb)[i] = sb;
        ((f32x4*)out2)[i * 2]     = f32x4{0.f, 0.f, 0.f, 0.f};
        ((f32x4*)out2)[i * 2 + 1] = f32x4{0.f, 0.f, 0.f, 0.f};
    } else {
        const int j = i - BATCH * DIM / 8;       // < 131072
        f32x4 v0 = ((const f32x4*)A)[j * 2];
        f32x4 v1 = ((const f32x4*)A)[j * 2 + 1];
        u16x8 ab;
#pragma unroll
        for (int e = 0; e < 4; ++e) {
            ab[e]     = f2bf(v0[e]);
            ab[e + 4] = f2bf(v1[e]);
        }
        ((u16x8*)Abf)[j] = ab;
    }
}

// ---------------------------------------------------------------------------
// K2: GEMM 128x64, R15 pipeline (glds, 3-buffer, counted vmcnt, raw barrier)
//   + EPILOGUE READ-SET PREFETCHED INTO REGISTERS before the K-loop:
//   12 f32x4/thread (x/ex/W), issued after stage(0..1). HBM read latency/BW
//   hides under the L2-bound K-loop. vmcnt schedule: 15,15,3,...,3,0.
//   512 thr (8 waves, 4x2 grid, acc[2][2]); LDS 72K; 2 blocks/CU.
// ---------------------------------------------------------------------------
__global__ __launch_bounds__(512, 4) void gemm_kernel(
    const float* __restrict__ x, const float* __restrict__ ex,
    const float* __restrict__ W, const float* __restrict__ tgt,
    const unsigned short* __restrict__ sigb,
    const unsigned short* __restrict__ Abf,
    float* __restrict__ out0, float* __restrict__ out1)
{
    __shared__ __align__(16) char lds[3 * BUF];

    // ---- block mapping: same-bm blocks share an XCD (sigb/x L2 reuse)
    const int b     = blockIdx.x;
    const int xcd   = b & 7;
    const int local = b >> 3;                    // 0..127
    const int bm    = xcd * 8 + (local >> 4);    // 0..63
    const int bn    = local & 15;                // 0..15

    const int tid  = threadIdx.x;
    const int lane = tid & 63;
    const int wid  = tid >> 6;                   // 0..7
    const int wr   = wid >> 1, wc = wid & 1;     // 4x2 wave grid
    const int l15  = lane & 15;

    // ---- staging source addresses (pre-swizzled source, linear LDS dest)
    const int swz = (((lane & 7) ^ (lane >> 3)) << 4);
    const char* gS = (const char*)sigb +
        ((size_t)(bm * BM + wid * 8 + (lane >> 3)) * DIM) * 2 + swz;
    const char* gB = (const char*)Abf +
        ((size_t)(bn * BN + wid * 8 + (lane >> 3)) * DIM) * 2 + swz;

    // ---- fragment read constants
    const int rd_sw = (lane & 7) << 4;
    const int cb0   = (lane >> 4) << 4;

    f32x4 acc[2][2];
#pragma unroll
    for (int mi = 0; mi < 2; ++mi)
#pragma unroll
        for (int ni = 0; ni < 2; ++ni)
            acc[mi][ni] = f32x4{0.f, 0.f, 0.f, 0.f};

    auto stage = [&](int t) {                    // 3 glds per wave
        char* As = lds + (t % 3) * BUF;
        char* Bs = As + 16384;
        const size_t ko = (size_t)t * (BK * 2);
#pragma unroll
        for (int j = 0; j < 2; ++j)
            __builtin_amdgcn_global_load_lds(
                AS1(gS + (size_t)j * (64 * DIM * 2) + ko),
                AS3(As + (wid * 8 + j * 64) * 128), 16, 0, 0);
        __builtin_amdgcn_global_load_lds(
            AS1(gB + ko), AS3(Bs + wid * 8 * 128), 16, 0, 0);
    };

    // ---- prologue: two stages in flight, then epilogue read-set prefetch
    stage(0);
    stage(1);

    f32x4 eX[4], eE[4], eW[4];
#pragma unroll
    for (int p = 0; p < 4; ++p) {
        const int ci  = p * 512 + tid;           // 0..2047
        const int row = ci >> 4;                 // 0..127
        const int cv  = ci & 15;                 // 0..15
        const size_t v4 = (size_t)(bm * BM + row) * (DIM / 4) + bn * 16 + cv;
        eX[p] = ((const f32x4*)x)[v4];
        eE[p] = ((const f32x4*)ex)[v4];
        eW[p] = ((const f32x4*)W)[v4];
    }
    __builtin_amdgcn_sched_barrier(0);

    // ---- main loop: counted wait + raw barrier per step
    for (int t = 0; t < STEPS; ++t) {
        __builtin_amdgcn_sched_barrier(0);
        if (t < 2)              asm volatile("s_waitcnt vmcnt(15)" ::: "memory");
        else if (t < STEPS - 1) asm volatile("s_waitcnt vmcnt(3)"  ::: "memory");
        else                    asm volatile("s_waitcnt vmcnt(0)"  ::: "memory");
        __builtin_amdgcn_sched_barrier(0);
        __builtin_amdgcn_s_barrier();
        __builtin_amdgcn_sched_barrier(0);
        if (t + 2 < STEPS) stage(t + 2);
        __builtin_amdgcn_sched_barrier(0);

        const char* As_ = lds + (t % 3) * BUF;
        const char* Bs_ = As_ + 16384;
#pragma unroll
        for (int kk = 0; kk < 2; ++kk) {
            bf16x8 af[2], bfr[2];
#pragma unroll
            for (int mi = 0; mi < 2; ++mi)
                af[mi] = *(const bf16x8*)(As_ + (wr * 32 + mi * 16 + l15) * 128 +
                                          ((cb0 + kk * 64) ^ rd_sw));
#pragma unroll
            for (int ni = 0; ni < 2; ++ni)
                bfr[ni] = *(const bf16x8*)(Bs_ + (wc * 32 + ni * 16 + l15) * 128 +
                                           ((cb0 + kk * 64) ^ rd_sw));
#pragma unroll
            for (int mi = 0; mi < 2; ++mi)
#pragma unroll
                for (int ni = 0; ni < 2; ++ni)
                    acc[mi][ni] = __builtin_amdgcn_mfma_f32_16x16x32_bf16(
                        af[mi], bfr[ni], acc[mi][ni], 0, 0, 0);
        }
    }

    // ---- epilogue: C -> LDS f32[128][64] (linear), then register epilogue
    __syncthreads();
#pragma unroll
    for (int mi = 0; mi < 2; ++mi)
#pragma unroll
        for (int ni = 0; ni < 2; ++ni) {
            const int row_ = wr * 32 + mi * 16 + ((lane >> 4) << 2);
            const int colb = (wc * 32 + ni * 16 + l15) * 4;
#pragma unroll
            for (int r = 0; r < 4; ++r)
                *(float*)(lds + (row_ + r) * 256 + colb) = acc[mi][ni][r];
        }
    __syncthreads();

#pragma unroll
    for (int p = 0; p < 4; ++p) {
        const int ci  = p * 512 + tid;           // 0..2047
        const int row = ci >> 4;                 // 0..127
        const int cv  = ci & 15;                 // 0..15
        f32x4 c = *(const f32x4*)(lds + row * 256 + cv * 16);
        const size_t v4 = (size_t)(bm * BM + row) * (DIM / 4) + bn * 16 + cv;
        f32x4 tv = ((const f32x4*)tgt)[bn * 16 + cv];
        f32x4 o0;
#pragma unroll
        for (int e = 0; e < 4; ++e) {
            float xi = eX[p][e], ti = tv[e];
            float ba = ti * ti * __builtin_amdgcn_rcpf(1.0f + ti * ti);
            float u  = -(eW[p][e] * (xi + eE[p][e] - ti)) * ba;
            float s  = sigma_f(xi);
            o0[e] = -xi + u * s + c[e];
        }
        ((f32x4*)out0)[v4] = o0;
        ((f32x4*)out1)[v4] = -o0;
    }
}

// ---------------------------------------------------------------------------
extern "C" void kernel_launch(void* const* d_in, const int* in_sizes, int n_in,
                              void* d_out, int out_size, void* d_ws, size_t ws_size,
                              hipStream_t stream)
{
    const float* x   = (const float*)d_in[0];
    const float* ex  = (const float*)d_in[1];
    const float* W   = (const float*)d_in[2];
    const float* A   = (const float*)d_in[3];
    const float* tgt = (const float*)d_in[4];

    float* out0 = (float*)d_out;
    float* out1 = out0 + (size_t)BATCH * DIM;
    float* out2 = out1 + (size_t)BATCH * DIM;

    unsigned short* sigb = (unsigned short*)d_ws;                                   // 16 MiB
    unsigned short* Abf  = (unsigned short*)((char*)d_ws + (size_t)16 * 1024 * 1024); // 2 MiB

    prep_kernel<<<4608, 256, 0, stream>>>(x, A, sigb, Abf, out2);
    gemm_kernel<<<(BATCH / BM) * (DIM / BN), 512, 0, stream>>>(
        x, ex, W, tgt, sigb, Abf, out0, out1);
}